// Round 2
// baseline (654.848 us; speedup 1.0000x reference)
//
#include <hip/hip_runtime.h>
#include <math.h>

// AxileAttention: out = softmax((X@Wq+bq)*(X@Wk+bk), -1) * (X@Wv+bv), per (b,c).
// B=8 C=64 H=256 W=256, fp32 in/out.
//
// Round 9: kill the W-staging critical path. R8 post-mortem: doubling occupancy
// gave only -7% -> latency-bound on the per-kt chain {barrier, 16 scalar W
// loads, ~100 convert VALU, barrier}, repeated 32x per block and redundantly
// re-converted by 32 blocks per channel (VALU 88us + MFMA 51us << 351us dur).
// Fix: prep kernel converts W once into f16 hi/lo planes in d_ws, laid out in
// MFMA fragment order. Main kernel W staging = 4 (ph1) / 1 (ph2)
// global_load_lds 16B issues per thread: no VALU, no VGPRs, half the W bytes,
// f16 weights (640KB/ch) L2-resident. Grid reordered so same-(c,ht) blocks
// across b are co-resident (bias slices were re-fetched ~8x).
// Fallback to R8-style kernel if ws_size < 40MB.

#define Bn 8
#define Cn 64
#define Hn 256
#define Wn 256

typedef _Float16 f16x8 __attribute__((ext_vector_type(8)));
typedef _Float16 f16x4 __attribute__((ext_vector_type(4)));
typedef float    f32x16 __attribute__((ext_vector_type(16)));

#define MFMA(a, b, c) __builtin_amdgcn_mfma_f32_32x32x16_f16((a), (b), (c), 0, 0, 0)

// LDS layout (39.4 KB -> 2 blocks/CU = 16 waves/CU):
//   A hi: [0,2048)       mtile*1024 + slot*16
//   A lo: [2048,4096)
//   B:    [4096,36864)   plane p*8192 + ntile*1024 + slot*16
//         phase1 planes: 0=qh 1=ql 2=kh 3=kl; phase2: plane 0 = vh
//   smx:  [36864,39424)  part[8][64] @0, combmax[64] @2048, combsum[64] @2304
#define LDS_ALO 2048
#define LDS_B   4096
#define LDS_SM  36864

// ws layout: plane(c,kt,p) = ((c*16+kt)*5+p) * 8192 bytes, p: 0=qh 1=ql 2=kh 3=kl 4=vh
// within plane: ntile*1024 + (khalf*32+nl)*16 bytes = f16x8 of rows k0+khalf*8..+8 at col n
#define WS_PLANE_H 4096   // halves per plane
#define WS_NEED ((size_t)Cn * 16 * 5 * 8192)

__device__ __forceinline__ void ldst16(const void* g, void* l) {
    __builtin_amdgcn_global_load_lds(
        (const __attribute__((address_space(1))) unsigned int*)g,
        (__attribute__((address_space(3))) unsigned int*)l, 16, 0, 0);
}

// ---------------- prep: W (f32) -> fragment-ordered f16 hi/lo planes ----------------
__global__ __launch_bounds__(256) void prep_w(
    const float* __restrict__ wq, const float* __restrict__ wk,
    const float* __restrict__ wv, _Float16* __restrict__ wf)
{
    const int blk = blockIdx.x;          // c*16 + kt
    const int kt  = blk & 15;
    const int c   = blk >> 4;
    const int n   = threadIdx.x;         // column 0..255
    const int ntile = n >> 5;
    const int nl    = n & 31;

    _Float16* base = wf + (size_t)blk * 5 * WS_PLANE_H;
    const size_t woff = ((size_t)c * Wn + kt * 16) * Wn + n;

#pragma unroll
    for (int mat = 0; mat < 2; ++mat) {      // 0=q, 1=k : hi+lo planes
        const float* Wp = (mat ? wk : wq) + woff;
        float w16[16];
#pragma unroll
        for (int r = 0; r < 16; ++r)
            w16[r] = Wp[(size_t)r * Wn];
        _Float16* hip = base + (mat * 2) * WS_PLANE_H + ntile * 512;
        _Float16* lop = hip + WS_PLANE_H;
#pragma unroll
        for (int h2 = 0; h2 < 2; ++h2) {
            f16x8 hi8, lo8;
#pragma unroll
            for (int e = 0; e < 8; ++e) {
                const float wv_ = w16[h2 * 8 + e];
                _Float16 hv = (_Float16)wv_;
                hi8[e] = hv;
                lo8[e] = (_Float16)(wv_ - (float)hv);
            }
            *(f16x8*)(hip + (h2 * 32 + nl) * 8) = hi8;
            *(f16x8*)(lop + (h2 * 32 + nl) * 8) = lo8;
        }
    }
    {   // v: hi only (plane 4)
        const float* Wp = wv + woff;
        float w16[16];
#pragma unroll
        for (int r = 0; r < 16; ++r)
            w16[r] = Wp[(size_t)r * Wn];
        _Float16* vp = base + 4 * WS_PLANE_H + ntile * 512;
#pragma unroll
        for (int h2 = 0; h2 < 2; ++h2) {
            f16x8 hi8;
#pragma unroll
            for (int e = 0; e < 8; ++e)
                hi8[e] = (_Float16)w16[h2 * 8 + e];
            *(f16x8*)(vp + (h2 * 32 + nl) * 8) = hi8;
        }
    }
}

// ---------------- main: prepped-W path ----------------
__global__ __launch_bounds__(512, 4) void axile_attn_mfma5(
    const float* __restrict__ x,
    const _Float16* __restrict__ wf,
    const float* __restrict__ bq,
    const float* __restrict__ bk,
    const float* __restrict__ bv,
    float* __restrict__ out)
{
    __shared__ __align__(16) char lds[39424];

    const int tid  = threadIdx.x;
    const int ncol = tid >> 6;     // wave id = column strip 0..7
    const int lane = tid & 63;
    const int h    = lane >> 5;
    const int l31  = lane & 31;

    // blk = ((ht*8 + b)*64) + c : c in low bits (XCD affinity), b varies within
    // a resident round (bias slice (c,ht) shared by 8 co-resident blocks).
    const int blk = blockIdx.x;
    const int c   = blk & 63;
    const int j   = blk >> 6;      // ht*8 + b
    const int b   = j & 7;
    const int h0  = (j >> 3) * 64;

    const float* xbase = x + ((size_t)(b * Cn + c) * Hn + h0) * Wn;
    const _Float16* wfc = wf + (size_t)c * 16 * 5 * WS_PLANE_H;

    // X staging (tid<256): thread = (row m = tid>>2, kq = tid&3) -> float4.
    const int am    = tid >> 2;          // 0..63
    const int akq   = tid & 3;
    const int amt   = am >> 5;
    const int alc   = ((akq >> 1) << 5) | (am & 31);
    const int aboff = (akq & 1) * 8;

    f32x16 accq[2], acck[2];
#pragma unroll
    for (int mt = 0; mt < 2; ++mt)
#pragma unroll
        for (int r = 0; r < 16; ++r) {
            accq[mt][r] = 0.f;
            acck[mt][r] = 0.f;
        }

    // ================= phase 1: q,k =================
    for (int kt = 0; kt < 16; ++kt) {
        const int k0 = kt * 16;
        const _Float16* wsp = wfc + (size_t)kt * 5 * WS_PLANE_H;
        __syncthreads();
        // W: 4 planes (qh,ql,kh,kl) direct global->LDS, fragment-ordered
#pragma unroll
        for (int p = 0; p < 4; ++p)
            ldst16(wsp + p * WS_PLANE_H + tid * 8,
                   lds + LDS_B + p * 8192 + tid * 16);
        // X (hi+lo) — first 4 waves only
        if (tid < 256) {
            const float4 xx = *(const float4*)(xbase + (size_t)am * Wn + k0 + akq * 4);
            f16x4 hi4, lo4;
            _Float16 t0 = (_Float16)xx.x; hi4[0] = t0; lo4[0] = (_Float16)(xx.x - (float)t0);
            _Float16 t1 = (_Float16)xx.y; hi4[1] = t1; lo4[1] = (_Float16)(xx.y - (float)t1);
            _Float16 t2 = (_Float16)xx.z; hi4[2] = t2; lo4[2] = (_Float16)(xx.z - (float)t2);
            _Float16 t3 = (_Float16)xx.w; hi4[3] = t3; lo4[3] = (_Float16)(xx.w - (float)t3);
            *(f16x4*)(lds + amt * 1024 + alc * 16 + aboff) = hi4;
            *(f16x4*)(lds + LDS_ALO + amt * 1024 + alc * 16 + aboff) = lo4;
        }
        __syncthreads();

        f16x8 ah[2], al[2];
#pragma unroll
        for (int mt = 0; mt < 2; ++mt) {
            ah[mt] = *(const f16x8*)(lds + mt * 1024 + lane * 16);
            al[mt] = *(const f16x8*)(lds + LDS_ALO + mt * 1024 + lane * 16);
        }
        const char* bb = lds + LDS_B + ncol * 1024 + lane * 16;
        f16x8 bqh = *(const f16x8*)(bb + 0 * 8192);
        f16x8 bql = *(const f16x8*)(bb + 1 * 8192);
        f16x8 bkh = *(const f16x8*)(bb + 2 * 8192);
        f16x8 bkl = *(const f16x8*)(bb + 3 * 8192);
#pragma unroll
        for (int mt = 0; mt < 2; ++mt) {
            accq[mt] = MFMA(ah[mt], bqh, accq[mt]);
            accq[mt] = MFMA(al[mt], bqh, accq[mt]);
            accq[mt] = MFMA(ah[mt], bql, accq[mt]);
            acck[mt] = MFMA(ah[mt], bkh, acck[mt]);
            acck[mt] = MFMA(al[mt], bkh, acck[mt]);
            acck[mt] = MFMA(ah[mt], bkl, acck[mt]);
        }
    }

    float* part    = (float*)(lds + LDS_SM);          // [8][64] wave-major
    float* combmax = (float*)(lds + LDS_SM + 2048);   // [64]
    float* combsum = (float*)(lds + LDS_SM + 2304);   // [64]

    // ---- bias add; s = q*k into accq (acck dies here) ----
#pragma unroll
    for (int mt = 0; mt < 2; ++mt)
#pragma unroll
        for (int r = 0; r < 16; ++r) {
            const int rl = (r & 3) + 8 * (r >> 2) + 4 * h;
            const int hh = h0 + mt * 32 + rl;
            const int vv = ncol * 32 + l31;
            const size_t bidx = ((size_t)c * Hn + hh) * Wn + vv;
            const float qv = accq[mt][r] + bq[bidx];
            const float kv = acck[mt][r] + bk[bidx];
            accq[mt][r] = qv * kv;
        }

    // ---- row max ----
#pragma unroll
    for (int mt = 0; mt < 2; ++mt)
#pragma unroll
        for (int r = 0; r < 16; ++r) {
            float m2 = accq[mt][r];
#pragma unroll
            for (int off = 16; off > 0; off >>= 1)
                m2 = fmaxf(m2, __shfl_xor(m2, off, 64));
            if ((lane & 15) == r && ((lane >> 4) & 1) == mt) {
                const int rl  = (r & 3) + 8 * (r >> 2) + 4 * h;
                const int row = mt * 32 + rl;
                part[ncol * 64 + row] = m2;
            }
        }
    __syncthreads();
    if (tid < 64) {
        float m = part[tid];
#pragma unroll
        for (int w = 1; w < 8; ++w)
            m = fmaxf(m, part[w * 64 + tid]);
        combmax[tid] = m;
    }
    __syncthreads();

    // ---- e = exp(s - mx); row sum ----
#pragma unroll
    for (int mt = 0; mt < 2; ++mt)
#pragma unroll
        for (int r = 0; r < 16; ++r) {
            const int rl  = (r & 3) + 8 * (r >> 2) + 4 * h;
            const int row = mt * 32 + rl;
            const float mx = combmax[row];
            const float e0 = __expf(accq[mt][r] - mx);
            accq[mt][r] = e0;
            float ps = e0;
#pragma unroll
            for (int off = 16; off > 0; off >>= 1)
                ps += __shfl_xor(ps, off, 64);
            if ((lane & 15) == r && ((lane >> 4) & 1) == mt)
                part[ncol * 64 + row] = ps;
        }
    __syncthreads();
    if (tid < 64) {
        float s = part[tid];
#pragma unroll
        for (int w = 1; w < 8; ++w)
            s += part[w * 64 + tid];
        combsum[tid] = s;
    }
    // (phase-2 first barrier covers combsum visibility)

    // ================= phase 2: v =================
    f32x16 accv[2];
#pragma unroll
    for (int mt = 0; mt < 2; ++mt)
#pragma unroll
        for (int r = 0; r < 16; ++r)
            accv[mt][r] = 0.f;

    for (int kt = 0; kt < 16; ++kt) {
        const int k0 = kt * 16;
        const _Float16* wsp = wfc + ((size_t)kt * 5 + 4) * WS_PLANE_H;  // vh plane
        __syncthreads();
        ldst16(wsp + tid * 8, lds + LDS_B + tid * 16);
        if (tid < 256) {
            const float4 xx = *(const float4*)(xbase + (size_t)am * Wn + k0 + akq * 4);
            f16x4 hi4;
            hi4[0] = (_Float16)xx.x;
            hi4[1] = (_Float16)xx.y;
            hi4[2] = (_Float16)xx.z;
            hi4[3] = (_Float16)xx.w;
            *(f16x4*)(lds + amt * 1024 + alc * 16 + aboff) = hi4;
        }
        __syncthreads();

        f16x8 ah[2];
#pragma unroll
        for (int mt = 0; mt < 2; ++mt)
            ah[mt] = *(const f16x8*)(lds + mt * 1024 + lane * 16);
        f16x8 bvh = *(const f16x8*)(lds + LDS_B + ncol * 1024 + lane * 16);
#pragma unroll
        for (int mt = 0; mt < 2; ++mt)
            accv[mt] = MFMA(ah[mt], bvh, accv[mt]);
    }

    // ---- out = e * (v + bv) / sum ----
    float* obase = out + ((size_t)(b * Cn + c) * Hn) * Wn;
#pragma unroll
    for (int mt = 0; mt < 2; ++mt)
#pragma unroll
        for (int r = 0; r < 16; ++r) {
            const int rl  = (r & 3) + 8 * (r >> 2) + 4 * h;
            const int row = mt * 32 + rl;
            const float inv = 1.0f / combsum[row];
            const int hh = h0 + row;
            const int vv = ncol * 32 + l31;
            const size_t bidx = ((size_t)c * Hn + hh) * Wn + vv;
            const float vx = accv[mt][r] + bv[bidx];
            obase[(size_t)hh * Wn + vv] = accq[mt][r] * vx * inv;
        }
}

// ---------------- fallback (R8): in-kernel W conversion, no ws ----------------
__global__ __launch_bounds__(512, 4) void axile_attn_mfma4(
    const float* __restrict__ x,
    const float* __restrict__ wq,
    const float* __restrict__ wk,
    const float* __restrict__ wv,
    const float* __restrict__ bq,
    const float* __restrict__ bk,
    const float* __restrict__ bv,
    float* __restrict__ out)
{
    __shared__ __align__(16) char lds[39424];

    const int tid  = threadIdx.x;
    const int ncol = tid >> 6;
    const int lane = tid & 63;
    const int h    = lane >> 5;
    const int l31  = lane & 31;

    const int blk = blockIdx.x;
    const int c   = blk & 63;
    const int j   = blk >> 6;
    const int b   = j & 7;
    const int h0  = (j >> 3) * 64;

    const float* xbase = x + ((size_t)(b * Cn + c) * Hn + h0) * Wn;
    const float* w_q = wq + (size_t)c * Wn * Wn;
    const float* w_k = wk + (size_t)c * Wn * Wn;
    const float* w_v = wv + (size_t)c * Wn * Wn;

    const int wkh = tid >> 8;
    const int n   = tid & 255;
    const int ntW = n >> 5;
    const int nl  = n & 31;
    const int wfo = ((wkh << 5) | nl) * 16;
    const int am    = tid >> 2;
    const int akq   = tid & 3;
    const int amt   = am >> 5;
    const int alc   = ((akq >> 1) << 5) | (am & 31);
    const int aboff = (akq & 1) * 8;

    f32x16 accq[2], acck[2];
#pragma unroll
    for (int mt = 0; mt < 2; ++mt)
#pragma unroll
        for (int r = 0; r < 16; ++r) {
            accq[mt][r] = 0.f;
            acck[mt][r] = 0.f;
        }

    for (int kt = 0; kt < 16; ++kt) {
        const int k0 = kt * 16;
        __syncthreads();
#pragma unroll
        for (int mat = 0; mat < 2; ++mat) {
            const float* Wp = mat ? w_k : w_q;
            const float* wrow = Wp + (size_t)(k0 + wkh * 8) * Wn + n;
            float w8[8];
#pragma unroll
            for (int r = 0; r < 8; ++r)
                w8[r] = wrow[(size_t)r * Wn];
            f16x8 hi8, lo8;
#pragma unroll
            for (int e = 0; e < 8; ++e) {
                const float wv_ = w8[e];
                _Float16 hv = (_Float16)wv_;
                hi8[e] = hv;
                lo8[e] = (_Float16)(wv_ - (float)hv);
            }
            char* dplane = lds + LDS_B + (mat * 2) * 8192 + ntW * 1024;
            *(f16x8*)(dplane + wfo) = hi8;
            *(f16x8*)(dplane + 8192 + wfo) = lo8;
        }
        if (tid < 256) {
            const float4 xx = *(const float4*)(xbase + (size_t)am * Wn + k0 + akq * 4);
            f16x4 hi4, lo4;
            _Float16 t0 = (_Float16)xx.x; hi4[0] = t0; lo4[0] = (_Float16)(xx.x - (float)t0);
            _Float16 t1 = (_Float16)xx.y; hi4[1] = t1; lo4[1] = (_Float16)(xx.y - (float)t1);
            _Float16 t2 = (_Float16)xx.z; hi4[2] = t2; lo4[2] = (_Float16)(xx.z - (float)t2);
            _Float16 t3 = (_Float16)xx.w; hi4[3] = t3; lo4[3] = (_Float16)(xx.w - (float)t3);
            *(f16x4*)(lds + amt * 1024 + alc * 16 + aboff) = hi4;
            *(f16x4*)(lds + LDS_ALO + amt * 1024 + alc * 16 + aboff) = lo4;
        }
        __syncthreads();

        f16x8 ah[2], al[2];
#pragma unroll
        for (int mt = 0; mt < 2; ++mt) {
            ah[mt] = *(const f16x8*)(lds + mt * 1024 + lane * 16);
            al[mt] = *(const f16x8*)(lds + LDS_ALO + mt * 1024 + lane * 16);
        }
        const char* bb = lds + LDS_B + ncol * 1024 + lane * 16;
        f16x8 bqh = *(const f16x8*)(bb + 0 * 8192);
        f16x8 bql = *(const f16x8*)(bb + 1 * 8192);
        f16x8 bkh = *(const f16x8*)(bb + 2 * 8192);
        f16x8 bkl = *(const f16x8*)(bb + 3 * 8192);
#pragma unroll
        for (int mt = 0; mt < 2; ++mt) {
            accq[mt] = MFMA(ah[mt], bqh, accq[mt]);
            accq[mt] = MFMA(al[mt], bqh, accq[mt]);
            accq[mt] = MFMA(ah[mt], bql, accq[mt]);
            acck[mt] = MFMA(ah[mt], bkh, acck[mt]);
            acck[mt] = MFMA(al[mt], bkh, acck[mt]);
            acck[mt] = MFMA(ah[mt], bkl, acck[mt]);
        }
    }

    float* part    = (float*)(lds + LDS_SM);
    float* combmax = (float*)(lds + LDS_SM + 2048);
    float* combsum = (float*)(lds + LDS_SM + 2304);

#pragma unroll
    for (int mt = 0; mt < 2; ++mt)
#pragma unroll
        for (int r = 0; r < 16; ++r) {
            const int rl = (r & 3) + 8 * (r >> 2) + 4 * h;
            const int hh = h0 + mt * 32 + rl;
            const int vv = ncol * 32 + l31;
            const size_t bidx = ((size_t)c * Hn + hh) * Wn + vv;
            const float qv = accq[mt][r] + bq[bidx];
            const float kv = acck[mt][r] + bk[bidx];
            accq[mt][r] = qv * kv;
        }

#pragma unroll
    for (int mt = 0; mt < 2; ++mt)
#pragma unroll
        for (int r = 0; r < 16; ++r) {
            float m2 = accq[mt][r];
#pragma unroll
            for (int off = 16; off > 0; off >>= 1)
                m2 = fmaxf(m2, __shfl_xor(m2, off, 64));
            if ((lane & 15) == r && ((lane >> 4) & 1) == mt) {
                const int rl  = (r & 3) + 8 * (r >> 2) + 4 * h;
                const int row = mt * 32 + rl;
                part[ncol * 64 + row] = m2;
            }
        }
    __syncthreads();
    if (tid < 64) {
        float m = part[tid];
#pragma unroll
        for (int w = 1; w < 8; ++w)
            m = fmaxf(m, part[w * 64 + tid]);
        combmax[tid] = m;
    }
    __syncthreads();

#pragma unroll
    for (int mt = 0; mt < 2; ++mt)
#pragma unroll
        for (int r = 0; r < 16; ++r) {
            const int rl  = (r & 3) + 8 * (r >> 2) + 4 * h;
            const int row = mt * 32 + rl;
            const float mx = combmax[row];
            const float e0 = __expf(accq[mt][r] - mx);
            accq[mt][r] = e0;
            float ps = e0;
#pragma unroll
            for (int off = 16; off > 0; off >>= 1)
                ps += __shfl_xor(ps, off, 64);
            if ((lane & 15) == r && ((lane >> 4) & 1) == mt)
                part[ncol * 64 + row] = ps;
        }
    __syncthreads();
    if (tid < 64) {
        float s = part[tid];
#pragma unroll
        for (int w = 1; w < 8; ++w)
            s += part[w * 64 + tid];
        combsum[tid] = s;
    }

    f32x16 accv[2];
#pragma unroll
    for (int mt = 0; mt < 2; ++mt)
#pragma unroll
        for (int r = 0; r < 16; ++r)
            accv[mt][r] = 0.f;

    for (int kt = 0; kt < 16; ++kt) {
        const int k0 = kt * 16;
        __syncthreads();
        {
            const float* wrow = w_v + (size_t)(k0 + wkh * 8) * Wn + n;
            float w8[8];
#pragma unroll
            for (int r = 0; r < 8; ++r)
                w8[r] = wrow[(size_t)r * Wn];
            f16x8 hi8;
#pragma unroll
            for (int e = 0; e < 8; ++e)
                hi8[e] = (_Float16)w8[e];
            *(f16x8*)(lds + LDS_B + ntW * 1024 + wfo) = hi8;
        }
        if (tid < 256) {
            const float4 xx = *(const float4*)(xbase + (size_t)am * Wn + k0 + akq * 4);
            f16x4 hi4;
            hi4[0] = (_Float16)xx.x;
            hi4[1] = (_Float16)xx.y;
            hi4[2] = (_Float16)xx.z;
            hi4[3] = (_Float16)xx.w;
            *(f16x4*)(lds + amt * 1024 + alc * 16 + aboff) = hi4;
        }
        __syncthreads();

        f16x8 ah[2];
#pragma unroll
        for (int mt = 0; mt < 2; ++mt)
            ah[mt] = *(const f16x8*)(lds + mt * 1024 + lane * 16);
        f16x8 bvh = *(const f16x8*)(lds + LDS_B + ncol * 1024 + lane * 16);
#pragma unroll
        for (int mt = 0; mt < 2; ++mt)
            accv[mt] = MFMA(ah[mt], bvh, accv[mt]);
    }

    float* obase = out + ((size_t)(b * Cn + c) * Hn) * Wn;
#pragma unroll
    for (int mt = 0; mt < 2; ++mt)
#pragma unroll
        for (int r = 0; r < 16; ++r) {
            const int rl  = (r & 3) + 8 * (r >> 2) + 4 * h;
            const int row = mt * 32 + rl;
            const float inv = 1.0f / combsum[row];
            const int hh = h0 + row;
            const int vv = ncol * 32 + l31;
            const size_t bidx = ((size_t)c * Hn + hh) * Wn + vv;
            const float vx = accv[mt][r] + bv[bidx];
            obase[(size_t)hh * Wn + vv] = accq[mt][r] * vx * inv;
        }
}

extern "C" void kernel_launch(void* const* d_in, const int* in_sizes, int n_in,
                              void* d_out, int out_size, void* d_ws, size_t ws_size,
                              hipStream_t stream) {
    (void)in_sizes; (void)n_in; (void)out_size;
    const float* x  = (const float*)d_in[0];
    const float* wq = (const float*)d_in[1];
    const float* wk = (const float*)d_in[2];
    const float* wv = (const float*)d_in[3];
    const float* bq = (const float*)d_in[4];
    const float* bk = (const float*)d_in[5];
    const float* bv = (const float*)d_in[6];
    float* out = (float*)d_out;

    if (d_ws != nullptr && ws_size >= WS_NEED) {
        hipLaunchKernelGGL(prep_w, dim3(Cn * 16), dim3(256), 0, stream,
                           wq, wk, wv, (_Float16*)d_ws);
        hipLaunchKernelGGL(axile_attn_mfma5, dim3(Bn * 4 * Cn), dim3(512), 0, stream,
                           x, (const _Float16*)d_ws, bq, bk, bv, out);
    } else {
        hipLaunchKernelGGL(axile_attn_mfma4, dim3(Bn * 4 * Cn), dim3(512), 0, stream,
                           x, wq, wk, wv, bq, bk, bv, out);
    }
}

// Round 3
// 519.599 us; speedup vs baseline: 1.2603x; 1.2603x over previous
//
#include <hip/hip_runtime.h>
#include <math.h>

// AxileAttention: out = softmax((X@Wq+bq)*(X@Wk+bk), -1) * (X@Wv+bv), per (b,c).
// B=8 C=64 H=256 W=256, fp32 in/out.
//
// Round 10: double-buffered pipeline. R9 post-mortem: prepped-W removed the
// convert VALU but that VALU was the only latency hiding -> per-kt chain
// {issue 4 ldst16, barrier(vmcnt0), 12 MFMA} exposed full load latency 32x;
// dur 351->454 despite clean FETCH (~ideal 510MB). Fix: 2x LDS buffers, ONE
// barrier per kt: issue X load + W global_load_lds for kt+1 into buf^1 BEFORE
// computing buf cur; X converts after MFMA (vmcnt(4) wait, not 0); barrier's
// vmcnt(0) is the counted drain with a full compute phase in its shadow.
// Phase-2 tile-0 staging hoisted above softmax (T14). Barriers 64->32.
// LDS 74.5KB -> still 2 blocks/CU. Prep kernel unchanged; R8 fallback kept.

#define Bn 8
#define Cn 64
#define Hn 256
#define Wn 256

typedef _Float16 f16x8 __attribute__((ext_vector_type(8)));
typedef _Float16 f16x4 __attribute__((ext_vector_type(4)));
typedef float    f32x16 __attribute__((ext_vector_type(16)));

#define MFMA(a, b, c) __builtin_amdgcn_mfma_f32_32x32x16_f16((a), (b), (c), 0, 0, 0)

// LDS layout (76288 B -> 2 blocks/CU = 16 waves/CU):
//   buf{0,1} at byte 0 / 36864, each:
//     A hi: [0,2048)       mtile*1024 + slot*16
//     A lo: [2048,4096)
//     B:    [4096,36864)   plane p*8192 + ntile*1024 + slot*16
//           phase1 planes: 0=qh 1=ql 2=kh 3=kl; phase2: plane 0 = vh
//   smx:  [73728,76288)  part[8][64] @0, combmax[64] @2048, combsum[64] @2304
#define LDS_BUF 36864
#define LDS_ALO 2048
#define LDS_B   4096
#define LDS_SM  73728

// ws layout: plane(c,kt,p) = ((c*16+kt)*5+p) * 8192 bytes, p: 0=qh 1=ql 2=kh 3=kl 4=vh
// within plane: ntile*1024 + (khalf*32+nl)*16 bytes = f16x8 of rows k0+khalf*8..+8 at col n
#define WS_PLANE_H 4096   // halves per plane
#define WS_NEED ((size_t)Cn * 16 * 5 * 8192)

__device__ __forceinline__ void ldst16(const void* g, void* l) {
    __builtin_amdgcn_global_load_lds(
        (const __attribute__((address_space(1))) unsigned int*)g,
        (__attribute__((address_space(3))) unsigned int*)l, 16, 0, 0);
}

// ---------------- prep: W (f32) -> fragment-ordered f16 hi/lo planes ----------------
__global__ __launch_bounds__(256) void prep_w(
    const float* __restrict__ wq, const float* __restrict__ wk,
    const float* __restrict__ wv, _Float16* __restrict__ wf)
{
    const int blk = blockIdx.x;          // c*16 + kt
    const int kt  = blk & 15;
    const int c   = blk >> 4;
    const int n   = threadIdx.x;         // column 0..255
    const int ntile = n >> 5;
    const int nl    = n & 31;

    _Float16* base = wf + (size_t)blk * 5 * WS_PLANE_H;
    const size_t woff = ((size_t)c * Wn + kt * 16) * Wn + n;

#pragma unroll
    for (int mat = 0; mat < 2; ++mat) {      // 0=q, 1=k : hi+lo planes
        const float* Wp = (mat ? wk : wq) + woff;
        float w16[16];
#pragma unroll
        for (int r = 0; r < 16; ++r)
            w16[r] = Wp[(size_t)r * Wn];
        _Float16* hip = base + (mat * 2) * WS_PLANE_H + ntile * 512;
        _Float16* lop = hip + WS_PLANE_H;
#pragma unroll
        for (int h2 = 0; h2 < 2; ++h2) {
            f16x8 hi8, lo8;
#pragma unroll
            for (int e = 0; e < 8; ++e) {
                const float wv_ = w16[h2 * 8 + e];
                _Float16 hv = (_Float16)wv_;
                hi8[e] = hv;
                lo8[e] = (_Float16)(wv_ - (float)hv);
            }
            *(f16x8*)(hip + (h2 * 32 + nl) * 8) = hi8;
            *(f16x8*)(lop + (h2 * 32 + nl) * 8) = lo8;
        }
    }
    {   // v: hi only (plane 4)
        const float* Wp = wv + woff;
        float w16[16];
#pragma unroll
        for (int r = 0; r < 16; ++r)
            w16[r] = Wp[(size_t)r * Wn];
        _Float16* vp = base + 4 * WS_PLANE_H + ntile * 512;
#pragma unroll
        for (int h2 = 0; h2 < 2; ++h2) {
            f16x8 hi8;
#pragma unroll
            for (int e = 0; e < 8; ++e)
                hi8[e] = (_Float16)w16[h2 * 8 + e];
            *(f16x8*)(vp + (h2 * 32 + nl) * 8) = hi8;
        }
    }
}

// ---------------- main: prepped-W, double-buffered pipeline ----------------
__global__ __launch_bounds__(512, 4) void axile_attn_mfma6(
    const float* __restrict__ x,
    const _Float16* __restrict__ wf,
    const float* __restrict__ bq,
    const float* __restrict__ bk,
    const float* __restrict__ bv,
    float* __restrict__ out)
{
    __shared__ __align__(16) char lds[76288];

    const int tid  = threadIdx.x;
    const int ncol = tid >> 6;     // wave id = column strip 0..7
    const int lane = tid & 63;
    const int h    = lane >> 5;
    const int l31  = lane & 31;

    // blk = ((ht*8 + b)*64) + c : c in low bits (XCD affinity per channel).
    const int blk = blockIdx.x;
    const int c   = blk & 63;
    const int j   = blk >> 6;      // ht*8 + b
    const int b   = j & 7;
    const int h0  = (j >> 3) * 64;

    const float* xbase = x + ((size_t)(b * Cn + c) * Hn + h0) * Wn;
    const _Float16* wfc = wf + (size_t)c * 16 * 5 * WS_PLANE_H;

    // X staging (tid<256): thread = (row m = tid>>2, kq = tid&3) -> float4.
    const int am    = tid >> 2;          // 0..63
    const int akq   = tid & 3;
    const int amt   = am >> 5;
    const int alc   = ((akq >> 1) << 5) | (am & 31);
    const int aboff = (akq & 1) * 8;
    const int axoff = amt * 1024 + alc * 16 + aboff;   // A-area byte offset

    f32x16 accq[2], acck[2];
#pragma unroll
    for (int mt = 0; mt < 2; ++mt)
#pragma unroll
        for (int r = 0; r < 16; ++r) {
            accq[mt][r] = 0.f;
            acck[mt][r] = 0.f;
        }

    // ---- phase-1 prologue: stage tile 0 into buf0 ----
    {
        if (tid < 256) {
            const float4 xx = *(const float4*)(xbase + (size_t)am * Wn + akq * 4);
            f16x4 hi4, lo4;
            _Float16 t0 = (_Float16)xx.x; hi4[0] = t0; lo4[0] = (_Float16)(xx.x - (float)t0);
            _Float16 t1 = (_Float16)xx.y; hi4[1] = t1; lo4[1] = (_Float16)(xx.y - (float)t1);
            _Float16 t2 = (_Float16)xx.z; hi4[2] = t2; lo4[2] = (_Float16)(xx.z - (float)t2);
            _Float16 t3 = (_Float16)xx.w; hi4[3] = t3; lo4[3] = (_Float16)(xx.w - (float)t3);
            *(f16x4*)(lds + axoff) = hi4;
            *(f16x4*)(lds + LDS_ALO + axoff) = lo4;
        }
#pragma unroll
        for (int p = 0; p < 4; ++p)
            ldst16(wfc + p * WS_PLANE_H + tid * 8,
                   lds + LDS_B + p * 8192 + tid * 16);
        __syncthreads();
    }

    // ================= phase 1: q,k =================
    int curo = 0;
    for (int kt = 0; kt < 16; ++kt) {
        const int nxto = curo ^ LDS_BUF;
        float4 xx;
        if (kt < 15) {
            // X load FIRST (converts later wait vmcnt(4), not vmcnt(0))
            if (tid < 256)
                xx = *(const float4*)(xbase + (size_t)am * Wn + (kt + 1) * 16 + akq * 4);
            const _Float16* wsp = wfc + (size_t)(kt + 1) * 5 * WS_PLANE_H;
#pragma unroll
            for (int p = 0; p < 4; ++p)
                ldst16(wsp + p * WS_PLANE_H + tid * 8,
                       lds + nxto + LDS_B + p * 8192 + tid * 16);
        }

        f16x8 ah[2], al[2];
#pragma unroll
        for (int mt = 0; mt < 2; ++mt) {
            ah[mt] = *(const f16x8*)(lds + curo + mt * 1024 + lane * 16);
            al[mt] = *(const f16x8*)(lds + curo + LDS_ALO + mt * 1024 + lane * 16);
        }
        const char* bb = lds + curo + LDS_B + ncol * 1024 + lane * 16;
        f16x8 bqh = *(const f16x8*)(bb + 0 * 8192);
        f16x8 bql = *(const f16x8*)(bb + 1 * 8192);
        f16x8 bkh = *(const f16x8*)(bb + 2 * 8192);
        f16x8 bkl = *(const f16x8*)(bb + 3 * 8192);
#pragma unroll
        for (int mt = 0; mt < 2; ++mt) {
            accq[mt] = MFMA(ah[mt], bqh, accq[mt]);
            accq[mt] = MFMA(al[mt], bqh, accq[mt]);
            accq[mt] = MFMA(ah[mt], bql, accq[mt]);
            acck[mt] = MFMA(ah[mt], bkh, acck[mt]);
            acck[mt] = MFMA(al[mt], bkh, acck[mt]);
            acck[mt] = MFMA(ah[mt], bkl, acck[mt]);
        }

        if (kt < 15 && tid < 256) {
            f16x4 hi4, lo4;
            _Float16 t0 = (_Float16)xx.x; hi4[0] = t0; lo4[0] = (_Float16)(xx.x - (float)t0);
            _Float16 t1 = (_Float16)xx.y; hi4[1] = t1; lo4[1] = (_Float16)(xx.y - (float)t1);
            _Float16 t2 = (_Float16)xx.z; hi4[2] = t2; lo4[2] = (_Float16)(xx.z - (float)t2);
            _Float16 t3 = (_Float16)xx.w; hi4[3] = t3; lo4[3] = (_Float16)(xx.w - (float)t3);
            *(f16x4*)(lds + nxto + axoff) = hi4;
            *(f16x4*)(lds + nxto + LDS_ALO + axoff) = lo4;
        }
        __syncthreads();   // vmcnt(0)+lgkmcnt(0) drain: next tile ready, cur consumed
        curo = nxto;
    }
    // curo == 0 here (16 toggles)

    // ---- phase-2 tile-0 staging, hoisted above softmax (latency under VALU) ----
    float4 xx0;
    if (tid < 256)
        xx0 = *(const float4*)(xbase + (size_t)am * Wn + akq * 4);
    ldst16(wfc + 4 * WS_PLANE_H + tid * 8, lds + LDS_B + tid * 16);  // vh plane, kt=0 -> buf0

    float* part    = (float*)(lds + LDS_SM);          // [8][64] wave-major
    float* combmax = (float*)(lds + LDS_SM + 2048);   // [64]
    float* combsum = (float*)(lds + LDS_SM + 2304);   // [64]

    // ---- bias add; s = q*k into accq (acck dies here) ----
#pragma unroll
    for (int mt = 0; mt < 2; ++mt)
#pragma unroll
        for (int r = 0; r < 16; ++r) {
            const int rl = (r & 3) + 8 * (r >> 2) + 4 * h;
            const int hh = h0 + mt * 32 + rl;
            const int vv = ncol * 32 + l31;
            const size_t bidx = ((size_t)c * Hn + hh) * Wn + vv;
            const float qv = accq[mt][r] + bq[bidx];
            const float kv = acck[mt][r] + bk[bidx];
            accq[mt][r] = qv * kv;
        }

    // X-hi tile0 convert+write (buf0 A-area free since kt=14's barrier)
    if (tid < 256) {
        f16x4 hi4;
        hi4[0] = (_Float16)xx0.x;
        hi4[1] = (_Float16)xx0.y;
        hi4[2] = (_Float16)xx0.z;
        hi4[3] = (_Float16)xx0.w;
        *(f16x4*)(lds + axoff) = hi4;
    }

    // ---- row max ----
#pragma unroll
    for (int mt = 0; mt < 2; ++mt)
#pragma unroll
        for (int r = 0; r < 16; ++r) {
            float m2 = accq[mt][r];
#pragma unroll
            for (int off = 16; off > 0; off >>= 1)
                m2 = fmaxf(m2, __shfl_xor(m2, off, 64));
            if ((lane & 15) == r && ((lane >> 4) & 1) == mt) {
                const int rl  = (r & 3) + 8 * (r >> 2) + 4 * h;
                const int row = mt * 32 + rl;
                part[ncol * 64 + row] = m2;
            }
        }
    __syncthreads();
    if (tid < 64) {
        float m = part[tid];
#pragma unroll
        for (int w = 1; w < 8; ++w)
            m = fmaxf(m, part[w * 64 + tid]);
        combmax[tid] = m;
    }
    __syncthreads();

    // ---- e = exp(s - mx); row sum ----
#pragma unroll
    for (int mt = 0; mt < 2; ++mt)
#pragma unroll
        for (int r = 0; r < 16; ++r) {
            const int rl  = (r & 3) + 8 * (r >> 2) + 4 * h;
            const int row = mt * 32 + rl;
            const float mx = combmax[row];
            const float e0 = __expf(accq[mt][r] - mx);
            accq[mt][r] = e0;
            float ps = e0;
#pragma unroll
            for (int off = 16; off > 0; off >>= 1)
                ps += __shfl_xor(ps, off, 64);
            if ((lane & 15) == r && ((lane >> 4) & 1) == mt)
                part[ncol * 64 + row] = ps;
        }
    __syncthreads();
    if (tid < 64) {
        float s = part[tid];
#pragma unroll
        for (int w = 1; w < 8; ++w)
            s += part[w * 64 + tid];
        combsum[tid] = s;
    }
    // (phase-2 loop barriers cover combsum/staging visibility)

    // ================= phase 2: v =================
    f32x16 accv[2];
#pragma unroll
    for (int mt = 0; mt < 2; ++mt)
#pragma unroll
        for (int r = 0; r < 16; ++r)
            accv[mt][r] = 0.f;

    for (int kt = 0; kt < 16; ++kt) {
        const int nxto = curo ^ LDS_BUF;
        float4 xx;
        if (kt < 15) {
            if (tid < 256)
                xx = *(const float4*)(xbase + (size_t)am * Wn + (kt + 1) * 16 + akq * 4);
            ldst16(wfc + ((size_t)(kt + 1) * 5 + 4) * WS_PLANE_H + tid * 8,
                   lds + nxto + LDS_B + tid * 16);
        }

        f16x8 ah[2];
#pragma unroll
        for (int mt = 0; mt < 2; ++mt)
            ah[mt] = *(const f16x8*)(lds + curo + mt * 1024 + lane * 16);
        f16x8 bvh = *(const f16x8*)(lds + curo + LDS_B + ncol * 1024 + lane * 16);
#pragma unroll
        for (int mt = 0; mt < 2; ++mt)
            accv[mt] = MFMA(ah[mt], bvh, accv[mt]);

        if (kt < 15 && tid < 256) {
            f16x4 hi4;
            hi4[0] = (_Float16)xx.x;
            hi4[1] = (_Float16)xx.y;
            hi4[2] = (_Float16)xx.z;
            hi4[3] = (_Float16)xx.w;
            *(f16x4*)(lds + nxto + axoff) = hi4;
        }
        __syncthreads();
        curo = nxto;
    }

    // ---- out = e * (v + bv) / sum ----
    float* obase = out + ((size_t)(b * Cn + c) * Hn) * Wn;
#pragma unroll
    for (int mt = 0; mt < 2; ++mt)
#pragma unroll
        for (int r = 0; r < 16; ++r) {
            const int rl  = (r & 3) + 8 * (r >> 2) + 4 * h;
            const int row = mt * 32 + rl;
            const float inv = 1.0f / combsum[row];
            const int hh = h0 + row;
            const int vv = ncol * 32 + l31;
            const size_t bidx = ((size_t)c * Hn + hh) * Wn + vv;
            const float vx = accv[mt][r] + bv[bidx];
            obase[(size_t)hh * Wn + vv] = accq[mt][r] * vx * inv;
        }
}

// ---------------- fallback (R8): in-kernel W conversion, no ws ----------------
__global__ __launch_bounds__(512, 4) void axile_attn_mfma4(
    const float* __restrict__ x,
    const float* __restrict__ wq,
    const float* __restrict__ wk,
    const float* __restrict__ wv,
    const float* __restrict__ bq,
    const float* __restrict__ bk,
    const float* __restrict__ bv,
    float* __restrict__ out)
{
    __shared__ __align__(16) char lds[39424];

    const int tid  = threadIdx.x;
    const int ncol = tid >> 6;
    const int lane = tid & 63;
    const int h    = lane >> 5;
    const int l31  = lane & 31;

    const int blk = blockIdx.x;
    const int c   = blk & 63;
    const int j   = blk >> 6;
    const int b   = j & 7;
    const int h0  = (j >> 3) * 64;

    const float* xbase = x + ((size_t)(b * Cn + c) * Hn + h0) * Wn;
    const float* w_q = wq + (size_t)c * Wn * Wn;
    const float* w_k = wk + (size_t)c * Wn * Wn;
    const float* w_v = wv + (size_t)c * Wn * Wn;

    const int wkh = tid >> 8;
    const int n   = tid & 255;
    const int ntW = n >> 5;
    const int nl  = n & 31;
    const int wfo = ((wkh << 5) | nl) * 16;
    const int am    = tid >> 2;
    const int akq   = tid & 3;
    const int amt   = am >> 5;
    const int alc   = ((akq >> 1) << 5) | (am & 31);
    const int aboff = (akq & 1) * 8;

    f32x16 accq[2], acck[2];
#pragma unroll
    for (int mt = 0; mt < 2; ++mt)
#pragma unroll
        for (int r = 0; r < 16; ++r) {
            accq[mt][r] = 0.f;
            acck[mt][r] = 0.f;
        }

    for (int kt = 0; kt < 16; ++kt) {
        const int k0 = kt * 16;
        __syncthreads();
#pragma unroll
        for (int mat = 0; mat < 2; ++mat) {
            const float* Wp = mat ? w_k : w_q;
            const float* wrow = Wp + (size_t)(k0 + wkh * 8) * Wn + n;
            float w8[8];
#pragma unroll
            for (int r = 0; r < 8; ++r)
                w8[r] = wrow[(size_t)r * Wn];
            f16x8 hi8, lo8;
#pragma unroll
            for (int e = 0; e < 8; ++e) {
                const float wv_ = w8[e];
                _Float16 hv = (_Float16)wv_;
                hi8[e] = hv;
                lo8[e] = (_Float16)(wv_ - (float)hv);
            }
            char* dplane = lds + LDS_B + (mat * 2) * 8192 + ntW * 1024;
            *(f16x8*)(dplane + wfo) = hi8;
            *(f16x8*)(dplane + 8192 + wfo) = lo8;
        }
        if (tid < 256) {
            const float4 xx = *(const float4*)(xbase + (size_t)am * Wn + k0 + akq * 4);
            f16x4 hi4, lo4;
            _Float16 t0 = (_Float16)xx.x; hi4[0] = t0; lo4[0] = (_Float16)(xx.x - (float)t0);
            _Float16 t1 = (_Float16)xx.y; hi4[1] = t1; lo4[1] = (_Float16)(xx.y - (float)t1);
            _Float16 t2 = (_Float16)xx.z; hi4[2] = t2; lo4[2] = (_Float16)(xx.z - (float)t2);
            _Float16 t3 = (_Float16)xx.w; hi4[3] = t3; lo4[3] = (_Float16)(xx.w - (float)t3);
            *(f16x4*)(lds + amt * 1024 + alc * 16 + aboff) = hi4;
            *(f16x4*)(lds + LDS_ALO + amt * 1024 + alc * 16 + aboff) = lo4;
        }
        __syncthreads();

        f16x8 ah[2], al[2];
#pragma unroll
        for (int mt = 0; mt < 2; ++mt) {
            ah[mt] = *(const f16x8*)(lds + mt * 1024 + lane * 16);
            al[mt] = *(const f16x8*)(lds + LDS_ALO + mt * 1024 + lane * 16);
        }
        const char* bb = lds + LDS_B + ncol * 1024 + lane * 16;
        f16x8 bqh = *(const f16x8*)(bb + 0 * 8192);
        f16x8 bql = *(const f16x8*)(bb + 1 * 8192);
        f16x8 bkh = *(const f16x8*)(bb + 2 * 8192);
        f16x8 bkl = *(const f16x8*)(bb + 3 * 8192);
#pragma unroll
        for (int mt = 0; mt < 2; ++mt) {
            accq[mt] = MFMA(ah[mt], bqh, accq[mt]);
            accq[mt] = MFMA(al[mt], bqh, accq[mt]);
            accq[mt] = MFMA(ah[mt], bql, accq[mt]);
            acck[mt] = MFMA(ah[mt], bkh, acck[mt]);
            acck[mt] = MFMA(al[mt], bkh, acck[mt]);
            acck[mt] = MFMA(ah[mt], bkl, acck[mt]);
        }
    }

    float* part    = (float*)(lds + LDS_SM - 36864 + 36864);  // unused alias guard
    part           = (float*)(lds + 36864);
    float* combmax = (float*)(lds + 36864 + 2048);
    float* combsum = (float*)(lds + 36864 + 2304);

#pragma unroll
    for (int mt = 0; mt < 2; ++mt)
#pragma unroll
        for (int r = 0; r < 16; ++r) {
            const int rl = (r & 3) + 8 * (r >> 2) + 4 * h;
            const int hh = h0 + mt * 32 + rl;
            const int vv = ncol * 32 + l31;
            const size_t bidx = ((size_t)c * Hn + hh) * Wn + vv;
            const float qv = accq[mt][r] + bq[bidx];
            const float kv = acck[mt][r] + bk[bidx];
            accq[mt][r] = qv * kv;
        }

#pragma unroll
    for (int mt = 0; mt < 2; ++mt)
#pragma unroll
        for (int r = 0; r < 16; ++r) {
            float m2 = accq[mt][r];
#pragma unroll
            for (int off = 16; off > 0; off >>= 1)
                m2 = fmaxf(m2, __shfl_xor(m2, off, 64));
            if ((lane & 15) == r && ((lane >> 4) & 1) == mt) {
                const int rl  = (r & 3) + 8 * (r >> 2) + 4 * h;
                const int row = mt * 32 + rl;
                part[ncol * 64 + row] = m2;
            }
        }
    __syncthreads();
    if (tid < 64) {
        float m = part[tid];
#pragma unroll
        for (int w = 1; w < 8; ++w)
            m = fmaxf(m, part[w * 64 + tid]);
        combmax[tid] = m;
    }
    __syncthreads();

#pragma unroll
    for (int mt = 0; mt < 2; ++mt)
#pragma unroll
        for (int r = 0; r < 16; ++r) {
            const int rl  = (r & 3) + 8 * (r >> 2) + 4 * h;
            const int row = mt * 32 + rl;
            const float mx = combmax[row];
            const float e0 = __expf(accq[mt][r] - mx);
            accq[mt][r] = e0;
            float ps = e0;
#pragma unroll
            for (int off = 16; off > 0; off >>= 1)
                ps += __shfl_xor(ps, off, 64);
            if ((lane & 15) == r && ((lane >> 4) & 1) == mt)
                part[ncol * 64 + row] = ps;
        }
    __syncthreads();
    if (tid < 64) {
        float s = part[tid];
#pragma unroll
        for (int w = 1; w < 8; ++w)
            s += part[w * 64 + tid];
        combsum[tid] = s;
    }

    f32x16 accv[2];
#pragma unroll
    for (int mt = 0; mt < 2; ++mt)
#pragma unroll
        for (int r = 0; r < 16; ++r)
            accv[mt][r] = 0.f;

    for (int kt = 0; kt < 16; ++kt) {
        const int k0 = kt * 16;
        __syncthreads();
        {
            const float* wrow = w_v + (size_t)(k0 + wkh * 8) * Wn + n;
            float w8[8];
#pragma unroll
            for (int r = 0; r < 8; ++r)
                w8[r] = wrow[(size_t)r * Wn];
            f16x8 hi8;
#pragma unroll
            for (int e = 0; e < 8; ++e)
                hi8[e] = (_Float16)w8[e];
            *(f16x8*)(lds + LDS_B + ntW * 1024 + wfo) = hi8;
        }
        if (tid < 256) {
            const float4 xx = *(const float4*)(xbase + (size_t)am * Wn + k0 + akq * 4);
            f16x4 hi4;
            hi4[0] = (_Float16)xx.x;
            hi4[1] = (_Float16)xx.y;
            hi4[2] = (_Float16)xx.z;
            hi4[3] = (_Float16)xx.w;
            *(f16x4*)(lds + amt * 1024 + alc * 16 + aboff) = hi4;
        }
        __syncthreads();

        f16x8 ah[2];
#pragma unroll
        for (int mt = 0; mt < 2; ++mt)
            ah[mt] = *(const f16x8*)(lds + mt * 1024 + lane * 16);
        f16x8 bvh = *(const f16x8*)(lds + LDS_B + ncol * 1024 + lane * 16);
#pragma unroll
        for (int mt = 0; mt < 2; ++mt)
            accv[mt] = MFMA(ah[mt], bvh, accv[mt]);
    }

    float* obase = out + ((size_t)(b * Cn + c) * Hn) * Wn;
#pragma unroll
    for (int mt = 0; mt < 2; ++mt)
#pragma unroll
        for (int r = 0; r < 16; ++r) {
            const int rl  = (r & 3) + 8 * (r >> 2) + 4 * h;
            const int row = mt * 32 + rl;
            const float inv = 1.0f / combsum[row];
            const int hh = h0 + row;
            const int vv = ncol * 32 + l31;
            const size_t bidx = ((size_t)c * Hn + hh) * Wn + vv;
            const float vx = accv[mt][r] + bv[bidx];
            obase[(size_t)hh * Wn + vv] = accq[mt][r] * vx * inv;
        }
}

extern "C" void kernel_launch(void* const* d_in, const int* in_sizes, int n_in,
                              void* d_out, int out_size, void* d_ws, size_t ws_size,
                              hipStream_t stream) {
    (void)in_sizes; (void)n_in; (void)out_size;
    const float* x  = (const float*)d_in[0];
    const float* wq = (const float*)d_in[1];
    const float* wk = (const float*)d_in[2];
    const float* wv = (const float*)d_in[3];
    const float* bq = (const float*)d_in[4];
    const float* bk = (const float*)d_in[5];
    const float* bv = (const float*)d_in[6];
    float* out = (float*)d_out;

    if (d_ws != nullptr && ws_size >= WS_NEED) {
        hipLaunchKernelGGL(prep_w, dim3(Cn * 16), dim3(256), 0, stream,
                           wq, wk, wv, (_Float16*)d_ws);
        hipLaunchKernelGGL(axile_attn_mfma6, dim3(Bn * 4 * Cn), dim3(512), 0, stream,
                           x, (const _Float16*)d_ws, bq, bk, bv, out);
    } else {
        hipLaunchKernelGGL(axile_attn_mfma4, dim3(Bn * 4 * Cn), dim3(512), 0, stream,
                           x, wq, wk, wv, bq, bk, bv, out);
    }
}